// Round 10
// baseline (17642.542 us; speedup 1.0000x reference)
//
#include <hip/hip_runtime.h>
#include <cmath>

// ---------- high-accuracy double transcendentals ----------
__device__ __forceinline__ double dexp_(double x) {
    x = fmin(fmax(x, -64.0), 64.0);
    double w = x * 1.4426950408889634;     // log2(e)
    double n = rint(w);
    double u = (w - n) * 0.6931471805599453;
    double p = 1.0 + u * (1.0 + u * (0.5 + u * (1.6666666666666666e-01 +
               u * (4.1666666666666664e-02 + u * (8.3333333333333332e-03 +
               u * (1.3888888888888889e-03 + u * (1.9841269841269841e-04 +
               u * (2.4801587301587302e-05 + u * (2.7557319223985893e-06 +
               u * (2.7557319223985888e-07 + u * 2.5052108385441720e-08))))))))));
    return ldexp(p, (int)n);
}
__device__ __forceinline__ double dtanh_(double x) {
    double ax = fabs(x);
    double e = dexp_(2.0 * ax);
    double t = 1.0 - 2.0 / (e + 1.0);
    return copysign(t, x);
}
__device__ __forceinline__ double dsig_(double x) {
    return 1.0 / (1.0 + dexp_(-x));
}

// 8-row FMA block, bit-identical op order to the verified kernel.
__device__ __forceinline__ void fma_range(
    const float* __restrict__ wcol, int row0, const float* __restrict__ xsrc,
    int k_beg, int k_end, double& A0, double& A1, double& A2, double& A3)
{
    for (int k0 = k_beg; k0 < k_end; k0 += 8) {
        float4 w[8];
        #pragma unroll
        for (int i = 0; i < 8; ++i)
            w[i] = *(const float4*)&wcol[(row0 + k0 + i) * 1024];
        float4 xa = *(const float4*)&xsrc[k0];
        float4 xb = *(const float4*)&xsrc[k0 + 4];
        float xv[8] = {xa.x, xa.y, xa.z, xa.w, xb.x, xb.y, xb.z, xb.w};
        float s0 = 0.f, s1 = 0.f, s2 = 0.f, s3 = 0.f;
        #pragma unroll
        for (int i = 0; i < 8; ++i) {
            s0 = fmaf(w[i].x, xv[i], s0);
            s1 = fmaf(w[i].y, xv[i], s1);
            s2 = fmaf(w[i].z, xv[i], s2);
            s3 = fmaf(w[i].w, xv[i], s3);
        }
        A0 += (double)s0; A1 += (double)s1;
        A2 += (double)s2; A3 += (double)s3;
    }
}

// Gate-interleaved transposed weights: W[k][j*4+g], fused interleaved biases bR[j*4+g].
__global__ __launch_bounds__(256) void prep_kernel(
    const float* __restrict__ eWih, const float* __restrict__ eWhh,
    const float* __restrict__ ebih, const float* __restrict__ ebhh,
    const float* __restrict__ dWih, const float* __restrict__ dWhh,
    const float* __restrict__ dbih, const float* __restrict__ dbhh,
    float* __restrict__ WencR, double* __restrict__ bencR,
    float* __restrict__ WdecR, double* __restrict__ bdecR)
{
    const int n_enc = 257 * 1024;
    const int n_dec = 513 * 1024;
    const int total = n_enc + n_dec + 2048;
    for (int idx = blockIdx.x * blockDim.x + threadIdx.x; idx < total;
         idx += gridDim.x * blockDim.x) {
        if (idx < n_enc) {
            int k = idx >> 10, c = idx & 1023;
            int j = c >> 2, g = c & 3, r = g * 256 + j;
            WencR[idx] = (k == 0) ? eWih[r] : eWhh[r * 256 + (k - 1)];
        } else if (idx < n_enc + n_dec) {
            int i2 = idx - n_enc;
            int k = i2 >> 10, c = i2 & 1023;
            int j = c >> 2, g = c & 3, r = g * 256 + j;
            WdecR[i2] = (k < 257) ? dWih[r * 257 + k] : dWhh[r * 256 + (k - 257)];
        } else {
            int c = idx - n_enc - n_dec;
            if (c < 1024) {
                int r = (c & 3) * 256 + (c >> 2);
                bencR[c] = (double)ebih[r] + (double)ebhh[r];
            } else {
                int c2 = c - 1024;
                int r = (c2 & 3) * 256 + (c2 >> 2);
                bdecR[c2] = (double)dbih[r] + (double)dbhh[r];
            }
        }
    }
}

// ===================== fused persistent encoder (R6-exact) =====================
// 256 blocks x 2 batches/block x 512 threads. Thread (bb = tid>>8, j = tid&255).
// bb-groups run in lockstep sharing the weight stream via cache.
__global__ __launch_bounds__(512) void enc_fused_kernel(
    const float* __restrict__ x, const float* __restrict__ W,
    const double* __restrict__ bR, float* __restrict__ enc_out,
    float* __restrict__ c_st)
{
    __shared__ float h_lds[2][2][256];
    __shared__ float xs[2][2];
    const int tid = threadIdx.x;
    const int bb  = tid >> 8;
    const int j   = tid & 255;
    const int b0g = blockIdx.x * 2;
    const int b   = b0g + bb;

    h_lds[0][bb][j] = 0.0f;
    float c_f = 0.f;
    const double bi = bR[j * 4 + 0], bf = bR[j * 4 + 1];
    const double bg = bR[j * 4 + 2], bo = bR[j * 4 + 3];
    const float* wcol = W + j * 4;

    for (int t = 0; t < 256; ++t) {
        const int cur = t & 1, nxt = cur ^ 1;
        if (tid < 2) xs[cur][tid] = x[(b0g + tid) * 256 + t];
        __syncthreads();   // publish h_lds[cur] (prev iter) and xs[cur]

        double A0 = 0, A1 = 0, A2 = 0, A3 = 0;
        const float* hh = h_lds[cur][bb];
        fma_range(wcol, 1, hh, 0, 256, A0, A1, A2, A3);
        {   // k = 0 : x_t
            float4 w = *(const float4*)&wcol[0];
            float xv = xs[cur][bb];
            A0 += (double)(w.x * xv); A1 += (double)(w.y * xv);
            A2 += (double)(w.z * xv); A3 += (double)(w.w * xv);
        }

        double iv = dsig_(A0 + bi);
        double fv = dsig_(A1 + bf);
        double gv = dtanh_(A2 + bg);
        double ov = dsig_(A3 + bo);
        double c = fv * (double)c_f + iv * gv;
        c_f = (float)c;
        float hv = (float)(ov * dtanh_(c));
        enc_out[(long)b * 65536 + t * 256 + j] = hv;
        h_lds[nxt][bb][j] = hv;
        __syncthreads();   // h_lds[nxt] complete before next iteration
    }

    c_st[(long)b * 256 + j] = c_f;   // handoff to decoder
}

// encW1d[m*10+u] = sum_h enc_out[m][h] * W1[u][h]  (fp64 accum, one-shot)
// NOTE: runs BEFORE the transpose (reads s-major layout).
__global__ __launch_bounds__(256) void encW1_kernel(
    const float* __restrict__ enc_out, const float* __restrict__ W1,
    double* __restrict__ encW1d)
{
    __shared__ float sa[64][260];
    __shared__ float sw[10][257];
    const int tid = threadIdx.x;
    const int m0 = blockIdx.x * 64;
    #pragma unroll
    for (int i = 0; i < 16; ++i) {
        int idx = tid + i * 256;
        int row = idx >> 6;
        int c4 = (idx & 63) * 4;
        const float4 v = *(const float4*)&enc_out[(long)(m0 + row) * 256 + c4];
        *(float4*)&sa[row][c4] = v;
    }
    for (int i = tid; i < 2560; i += 256) sw[i >> 8][i & 255] = W1[i];
    __syncthreads();
    for (int o = tid; o < 640; o += 256) {
        int r = o / 10;
        int u = o - r * 10;
        double acc = 0.0;
        #pragma unroll 4
        for (int k = 0; k < 256; ++k)
            acc += (double)sa[r][k] * (double)sw[u][k];
        encW1d[(long)(m0 + r) * 10 + u] = acc;
    }
}

// In-place per-batch transpose: enc_out[b][s][h] -> enc_out[b][h][s].
// One block per batch; 32x32 tile pairs swapped through LDS.
__global__ __launch_bounds__(256) void transpose_kernel(float* __restrict__ eo)
{
    __shared__ float ta[32][33], tb[32][33];
    const int tid = threadIdx.x;
    const int r   = tid >> 3;         // 0..31 (tile row)
    const int c4  = (tid & 7) * 4;    // 0,4,..,28 (tile col group)
    float* base = eo + (long)blockIdx.x * 65536;

    for (int ti = 0; ti < 8; ++ti) {
        for (int tj = ti; tj < 8; ++tj) {
            float4 va = *(const float4*)&base[(ti * 32 + r) * 256 + tj * 32 + c4];
            ta[r][c4 + 0] = va.x; ta[r][c4 + 1] = va.y;
            ta[r][c4 + 2] = va.z; ta[r][c4 + 3] = va.w;
            if (tj > ti) {
                float4 vb = *(const float4*)&base[(tj * 32 + r) * 256 + ti * 32 + c4];
                tb[r][c4 + 0] = vb.x; tb[r][c4 + 1] = vb.y;
                tb[r][c4 + 2] = vb.z; tb[r][c4 + 3] = vb.w;
            }
            __syncthreads();
            {   // write ta^T into (tj,ti)
                float4 w;
                w.x = ta[c4 + 0][r]; w.y = ta[c4 + 1][r];
                w.z = ta[c4 + 2][r]; w.w = ta[c4 + 3][r];
                *(float4*)&base[(tj * 32 + r) * 256 + ti * 32 + c4] = w;
            }
            if (tj > ti) {   // write tb^T into (ti,tj)
                float4 w;
                w.x = tb[c4 + 0][r]; w.y = tb[c4 + 1][r];
                w.z = tb[c4 + 2][r]; w.w = tb[c4 + 3][r];
                *(float4*)&base[(ti * 32 + r) * 256 + tj * 32 + c4] = w;
            }
            __syncthreads();
        }
    }
}

// ===================== fused persistent decoder =====================
// 512 blocks x 1 batch/block x 256 threads, __launch_bounds__(256,2):
// two co-resident blocks per CU = independent barrier domains (R9-verified).
// enc_out is h-major ([b][h][s]) here: phase B reads thread-j's row
// CONTIGUOUSLY via float4 (64 wide loads vs 256 scalars), accumulation
// order bit-identical to the verified 4-acc tree.
__global__ __launch_bounds__(256, 2) void dec_fused_kernel(
    const double* __restrict__ encW1d, const float* __restrict__ enc_out,
    const float* __restrict__ W2, const float* __restrict__ V,
    const float* __restrict__ x, const int* __restrict__ y,
    const float* __restrict__ W, const double* __restrict__ bR,
    const float* __restrict__ c_init, float* __restrict__ logp_buf,
    float* __restrict__ out_pred)
{
    __shared__ float h_lds[2][256];
    __shared__ float di_lds[256];
    __shared__ float e_lds[256];
    __shared__ float rcpZ_s;
    __shared__ float din_s;
    __shared__ double s_V[12];
    __shared__ double s_W2h[12];
    __shared__ double s_ld[256];
    __shared__ double s_red[4];
    __shared__ int s_redi[4];
    __shared__ double s_maxd;
    __shared__ int s_am;

    const int tid  = threadIdx.x;
    const int j    = tid;
    const int wid  = tid >> 6;
    const int lane = tid & 63;
    const int b    = blockIdx.x;

    if (tid < 10) s_V[tid] = (double)V[tid];
    h_lds[0][j] = enc_out[(long)b * 65536 + j * 256 + 255];   // h-major: [j][255]
    float c_f = c_init[(long)b * 256 + j];
    const double bi = bR[j * 4 + 0], bf = bR[j * 4 + 1];
    const double bg = bR[j * 4 + 2], bo = bR[j * 4 + 3];
    const float* wcol = W + j * 4;
    __syncthreads();

    for (int t = 0; t < 256; ++t) {
        const int cur = t & 1, nxt = cur ^ 1;
        const float* hh = h_lds[cur];

        // ---------------- phase A: attention softmax ----------------------
        for (int u = wid; u < 10; u += 4) {
            double p = 0.0;
            #pragma unroll
            for (int i = 0; i < 4; ++i) {
                int k = lane + i * 64;
                p += (double)W2[u * 256 + k] * (double)hh[k];
            }
            #pragma unroll
            for (int off = 32; off >= 1; off >>= 1) p += __shfl_down(p, off, 64);
            if (lane == 0) s_W2h[u] = p;
        }
        __syncthreads();

        const double* eW = encW1d + ((long)b * 256 + j) * 10;
        double l = 0.0;
        #pragma unroll
        for (int u = 0; u < 10; ++u) l += s_V[u] * dtanh_(eW[u] + s_W2h[u]);
        s_ld[j] = l;

        {   // argmax (first-index tie-break)
            double v = l; int idx = j;
            #pragma unroll
            for (int off = 32; off >= 1; off >>= 1) {
                double v2 = __shfl_down(v, off, 64);
                int i2 = __shfl_down(idx, off, 64);
                if (v2 > v || (v2 == v && i2 < idx)) { v = v2; idx = i2; }
            }
            if (lane == 0) { s_red[wid] = v; s_redi[wid] = idx; }
        }
        __syncthreads();
        if (tid == 0) {
            double v = s_red[0]; int idx = s_redi[0];
            #pragma unroll
            for (int w2 = 1; w2 < 4; ++w2) {
                if (s_red[w2] > v || (s_red[w2] == v && s_redi[w2] < idx)) {
                    v = s_red[w2]; idx = s_redi[w2];
                }
            }
            s_maxd = v; s_am = idx;
        }
        __syncthreads();

        double e = dexp_(l - s_maxd);
        e_lds[j] = (float)e;
        {
            double v = e;
            #pragma unroll
            for (int off = 32; off >= 1; off >>= 1) v += __shfl_down(v, off, 64);
            if (lane == 0) s_red[wid] = v;
        }
        __syncthreads();
        if (tid == 0) {
            double Z = s_red[0] + s_red[1] + s_red[2] + s_red[3];
            rcpZ_s = (float)(1.0 / Z);
            out_pred[t * 512 + b] = (float)s_am;
            int yv = y[b * 256 + t];
            logp_buf[t * 512 + b] = (float)(s_ld[yv] - s_maxd - log(Z));
        } else if (tid == 1) {   // dec_in (teacher forcing), independent
            float dv = 0.0f;
            if (t > 0) { int yi = y[b * 256 + (t - 1)]; dv = x[b * 256 + yi]; }
            din_s = dv;
        }
        __syncthreads();

        // ------- phase B: di GEMV, contiguous float4 reads (h-major) ------
        {
            const float* ep = enc_out + (long)b * 65536 + j * 256;
            float acc0 = 0.f, acc1 = 0.f, acc2 = 0.f, acc3 = 0.f;
            for (int s2 = 0; s2 < 256; s2 += 4) {
                float4 v = *(const float4*)&ep[s2];
                acc0 += e_lds[s2 + 0] * v.x;
                acc1 += e_lds[s2 + 1] * v.y;
                acc2 += e_lds[s2 + 2] * v.z;
                acc3 += e_lds[s2 + 3] * v.w;
            }
            di_lds[j] = ((acc0 + acc1) + (acc2 + acc3)) * rcpZ_s;
        }
        __syncthreads();   // di_lds ready

        // ---------------- dec LSTM ---------------------------------------
        double A0 = 0, A1 = 0, A2 = 0, A3 = 0;

        // region 1: di (weight rows 0..255)
        fma_range(wcol, 0, di_lds, 0, 256, A0, A1, A2, A3);
        {   // k = 256 : dec_in
            float4 w = *(const float4*)&wcol[256 * 1024];
            float xv = din_s;
            A0 += (double)(w.x * xv); A1 += (double)(w.y * xv);
            A2 += (double)(w.z * xv); A3 += (double)(w.w * xv);
        }
        // region 2: h (weight rows 257..512)
        fma_range(wcol, 257, hh, 0, 256, A0, A1, A2, A3);

        double iv = dsig_(A0 + bi);
        double fv = dsig_(A1 + bf);
        double gv = dtanh_(A2 + bg);
        double ov = dsig_(A3 + bo);
        double c = fv * (double)c_f + iv * gv;
        c_f = (float)c;
        h_lds[nxt][j] = (float)(ov * dtanh_(c));
        __syncthreads();   // publish h_lds[nxt]
    }
}

__global__ __launch_bounds__(256) void loss_kernel(
    const float* __restrict__ logp_buf, float* __restrict__ out)
{
    const int tid = threadIdx.x;
    double acc = 0.0;
    for (int i = tid; i < 131072; i += 256) acc += (double)logp_buf[i];
    __shared__ double s_red[4];
    const int wid = tid >> 6, lane = tid & 63;
    #pragma unroll
    for (int off = 32; off >= 1; off >>= 1) acc += __shfl_down(acc, off, 64);
    if (lane == 0) s_red[wid] = acc;
    __syncthreads();
    if (tid == 0) {
        out[131072] = (float)(-(s_red[0] + s_red[1] + s_red[2] + s_red[3])
                              / (512.0 * 512.0));
    }
}

extern "C" void kernel_launch(void* const* d_in, const int* in_sizes, int n_in,
                              void* d_out, int out_size, void* d_ws, size_t ws_size,
                              hipStream_t stream)
{
    const float* x    = (const float*)d_in[0];
    const int*   y    = (const int*)  d_in[1];
    const float* eWih = (const float*)d_in[2];
    const float* eWhh = (const float*)d_in[3];
    const float* ebih = (const float*)d_in[4];
    const float* ebhh = (const float*)d_in[5];
    const float* dWih = (const float*)d_in[6];
    const float* dWhh = (const float*)d_in[7];
    const float* dbih = (const float*)d_in[8];
    const float* dbhh = (const float*)d_in[9];
    const float* W1   = (const float*)d_in[10];
    const float* W2   = (const float*)d_in[11];
    const float* V    = (const float*)d_in[12];

    double* encW1d = (double*)d_ws;             // 1310720 doubles
    double* bencR  = encW1d + 1310720;          // 1024
    double* bdecR  = bencR + 1024;              // 1024
    float* enc_out = (float*)(bdecR + 1024);    // [512][256][256] (b,s,h) -> (b,h,s)
    float* c_st    = enc_out + 33554432;        // 131072
    float* hzero   = c_st + 131072;             // 131072 (unused)
    float* hd      = hzero + 131072;            // 2 x 131072 (unused)
    float* dibuf   = hd + 262144;               // 131072 (unused)
    float* logp    = dibuf + 131072;            // 131072
    float* WencR   = logp + 131072;             // 263168
    float* WdecR   = WencR + 263168;            // 525312

    float* out = (float*)d_out;

    prep_kernel<<<512, 256, 0, stream>>>(eWih, eWhh, ebih, ebhh,
                                         dWih, dWhh, dbih, dbhh,
                                         WencR, bencR, WdecR, bdecR);

    enc_fused_kernel<<<256, 512, 0, stream>>>(x, WencR, bencR, enc_out, c_st);

    encW1_kernel<<<2048, 256, 0, stream>>>(enc_out, W1, encW1d);

    transpose_kernel<<<512, 256, 0, stream>>>(enc_out);

    dec_fused_kernel<<<512, 256, 0, stream>>>(encW1d, enc_out, W2, V, x, y,
                                              WdecR, bdecR, c_st, logp, out);

    loss_kernel<<<1, 256, 0, stream>>>(logp, out);
}

// Round 11
// 17372.218 us; speedup vs baseline: 1.0156x; 1.0156x over previous
//
#include <hip/hip_runtime.h>
#include <cmath>

// ---------- high-accuracy double transcendentals ----------
__device__ __forceinline__ double dexp_(double x) {
    x = fmin(fmax(x, -64.0), 64.0);
    double w = x * 1.4426950408889634;     // log2(e)
    double n = rint(w);
    double u = (w - n) * 0.6931471805599453;
    double p = 1.0 + u * (1.0 + u * (0.5 + u * (1.6666666666666666e-01 +
               u * (4.1666666666666664e-02 + u * (8.3333333333333332e-03 +
               u * (1.3888888888888889e-03 + u * (1.9841269841269841e-04 +
               u * (2.4801587301587302e-05 + u * (2.7557319223985893e-06 +
               u * (2.7557319223985888e-07 + u * 2.5052108385441720e-08))))))))));
    return ldexp(p, (int)n);
}
__device__ __forceinline__ double dtanh_(double x) {
    double ax = fabs(x);
    double e = dexp_(2.0 * ax);
    double t = 1.0 - 2.0 / (e + 1.0);
    return copysign(t, x);
}
__device__ __forceinline__ double dsig_(double x) {
    return 1.0 / (1.0 + dexp_(-x));
}

// 8-row FMA block, bit-identical op order to the verified kernel.
__device__ __forceinline__ void fma_range(
    const float* __restrict__ wcol, int row0, const float* __restrict__ xsrc,
    int k_beg, int k_end, double& A0, double& A1, double& A2, double& A3)
{
    for (int k0 = k_beg; k0 < k_end; k0 += 8) {
        float4 w[8];
        #pragma unroll
        for (int i = 0; i < 8; ++i)
            w[i] = *(const float4*)&wcol[(row0 + k0 + i) * 1024];
        float4 xa = *(const float4*)&xsrc[k0];
        float4 xb = *(const float4*)&xsrc[k0 + 4];
        float xv[8] = {xa.x, xa.y, xa.z, xa.w, xb.x, xb.y, xb.z, xb.w};
        float s0 = 0.f, s1 = 0.f, s2 = 0.f, s3 = 0.f;
        #pragma unroll
        for (int i = 0; i < 8; ++i) {
            s0 = fmaf(w[i].x, xv[i], s0);
            s1 = fmaf(w[i].y, xv[i], s1);
            s2 = fmaf(w[i].z, xv[i], s2);
            s3 = fmaf(w[i].w, xv[i], s3);
        }
        A0 += (double)s0; A1 += (double)s1;
        A2 += (double)s2; A3 += (double)s3;
    }
}

// Gate-interleaved transposed weights: W[k][j*4+g], fused interleaved biases bR[j*4+g].
__global__ __launch_bounds__(256) void prep_kernel(
    const float* __restrict__ eWih, const float* __restrict__ eWhh,
    const float* __restrict__ ebih, const float* __restrict__ ebhh,
    const float* __restrict__ dWih, const float* __restrict__ dWhh,
    const float* __restrict__ dbih, const float* __restrict__ dbhh,
    float* __restrict__ WencR, double* __restrict__ bencR,
    float* __restrict__ WdecR, double* __restrict__ bdecR)
{
    const int n_enc = 257 * 1024;
    const int n_dec = 513 * 1024;
    const int total = n_enc + n_dec + 2048;
    for (int idx = blockIdx.x * blockDim.x + threadIdx.x; idx < total;
         idx += gridDim.x * blockDim.x) {
        if (idx < n_enc) {
            int k = idx >> 10, c = idx & 1023;
            int j = c >> 2, g = c & 3, r = g * 256 + j;
            WencR[idx] = (k == 0) ? eWih[r] : eWhh[r * 256 + (k - 1)];
        } else if (idx < n_enc + n_dec) {
            int i2 = idx - n_enc;
            int k = i2 >> 10, c = i2 & 1023;
            int j = c >> 2, g = c & 3, r = g * 256 + j;
            WdecR[i2] = (k < 257) ? dWih[r * 257 + k] : dWhh[r * 256 + (k - 257)];
        } else {
            int c = idx - n_enc - n_dec;
            if (c < 1024) {
                int r = (c & 3) * 256 + (c >> 2);
                bencR[c] = (double)ebih[r] + (double)ebhh[r];
            } else {
                int c2 = c - 1024;
                int r = (c2 & 3) * 256 + (c2 >> 2);
                bdecR[c2] = (double)dbih[r] + (double)dbhh[r];
            }
        }
    }
}

// ===================== fused persistent encoder =====================
// 512 blocks x 1 batch/block x 256 threads, __launch_bounds__(256,2):
// two co-resident blocks per CU = independent barrier domains (R9-verified
// transform). Per-unit arithmetic order identical; x_t read directly
// (same value as the LDS-broadcast path).
__global__ __launch_bounds__(256, 2) void enc_fused_kernel(
    const float* __restrict__ x, const float* __restrict__ W,
    const double* __restrict__ bR, float* __restrict__ enc_out,
    float* __restrict__ c_st)
{
    __shared__ float h_lds[2][256];
    const int tid = threadIdx.x;
    const int j   = tid;
    const int b   = blockIdx.x;

    h_lds[0][j] = 0.0f;
    float c_f = 0.f;
    const double bi = bR[j * 4 + 0], bf = bR[j * 4 + 1];
    const double bg = bR[j * 4 + 2], bo = bR[j * 4 + 3];
    const float* wcol = W + j * 4;

    for (int t = 0; t < 256; ++t) {
        const int cur = t & 1, nxt = cur ^ 1;
        __syncthreads();   // h_lds[cur] (prev iter) published

        double A0 = 0, A1 = 0, A2 = 0, A3 = 0;
        const float* hh = h_lds[cur];
        fma_range(wcol, 1, hh, 0, 256, A0, A1, A2, A3);
        {   // k = 0 : x_t
            float4 w = *(const float4*)&wcol[0];
            float xv = x[b * 256 + t];
            A0 += (double)(w.x * xv); A1 += (double)(w.y * xv);
            A2 += (double)(w.z * xv); A3 += (double)(w.w * xv);
        }

        double iv = dsig_(A0 + bi);
        double fv = dsig_(A1 + bf);
        double gv = dtanh_(A2 + bg);
        double ov = dsig_(A3 + bo);
        double c = fv * (double)c_f + iv * gv;
        c_f = (float)c;
        float hv = (float)(ov * dtanh_(c));
        enc_out[(long)b * 65536 + t * 256 + j] = hv;
        h_lds[nxt][j] = hv;
    }

    c_st[(long)b * 256 + j] = c_f;   // handoff to decoder
}

// encW1d[m*10+u] = sum_h enc_out[m][h] * W1[u][h]  (fp64 accum, one-shot)
// NOTE: runs BEFORE the transpose (reads s-major layout).
__global__ __launch_bounds__(256) void encW1_kernel(
    const float* __restrict__ enc_out, const float* __restrict__ W1,
    double* __restrict__ encW1d)
{
    __shared__ float sa[64][260];
    __shared__ float sw[10][257];
    const int tid = threadIdx.x;
    const int m0 = blockIdx.x * 64;
    #pragma unroll
    for (int i = 0; i < 16; ++i) {
        int idx = tid + i * 256;
        int row = idx >> 6;
        int c4 = (idx & 63) * 4;
        const float4 v = *(const float4*)&enc_out[(long)(m0 + row) * 256 + c4];
        *(float4*)&sa[row][c4] = v;
    }
    for (int i = tid; i < 2560; i += 256) sw[i >> 8][i & 255] = W1[i];
    __syncthreads();
    for (int o = tid; o < 640; o += 256) {
        int r = o / 10;
        int u = o - r * 10;
        double acc = 0.0;
        #pragma unroll 4
        for (int k = 0; k < 256; ++k)
            acc += (double)sa[r][k] * (double)sw[u][k];
        encW1d[(long)(m0 + r) * 10 + u] = acc;
    }
}

// In-place per-batch transpose: enc_out[b][s][h] -> enc_out[b][h][s].
__global__ __launch_bounds__(256) void transpose_kernel(float* __restrict__ eo)
{
    __shared__ float ta[32][33], tb[32][33];
    const int tid = threadIdx.x;
    const int r   = tid >> 3;         // 0..31 (tile row)
    const int c4  = (tid & 7) * 4;    // 0,4,..,28 (tile col group)
    float* base = eo + (long)blockIdx.x * 65536;

    for (int ti = 0; ti < 8; ++ti) {
        for (int tj = ti; tj < 8; ++tj) {
            float4 va = *(const float4*)&base[(ti * 32 + r) * 256 + tj * 32 + c4];
            ta[r][c4 + 0] = va.x; ta[r][c4 + 1] = va.y;
            ta[r][c4 + 2] = va.z; ta[r][c4 + 3] = va.w;
            if (tj > ti) {
                float4 vb = *(const float4*)&base[(tj * 32 + r) * 256 + ti * 32 + c4];
                tb[r][c4 + 0] = vb.x; tb[r][c4 + 1] = vb.y;
                tb[r][c4 + 2] = vb.z; tb[r][c4 + 3] = vb.w;
            }
            __syncthreads();
            {   // write ta^T into (tj,ti)
                float4 w;
                w.x = ta[c4 + 0][r]; w.y = ta[c4 + 1][r];
                w.z = ta[c4 + 2][r]; w.w = ta[c4 + 3][r];
                *(float4*)&base[(tj * 32 + r) * 256 + ti * 32 + c4] = w;
            }
            if (tj > ti) {   // write tb^T into (ti,tj)
                float4 w;
                w.x = tb[c4 + 0][r]; w.y = tb[c4 + 1][r];
                w.z = tb[c4 + 2][r]; w.w = tb[c4 + 3][r];
                *(float4*)&base[(ti * 32 + r) * 256 + tj * 32 + c4] = w;
            }
            __syncthreads();
        }
    }
}

// ===================== fused persistent decoder =====================
// 512 blocks x 1 batch/block x 256 threads, __launch_bounds__(256,2).
// NEW (R11): the batch's encW1d slice (transposed, [10][260] doubles) and
// W2 ([10][256] floats) are preloaded into LDS once — removes the serial
// per-step L3/HBM load at the head of phase A. Values and op order are
// bit-identical; only the operand source moves to LDS.
__global__ __launch_bounds__(256, 2) void dec_fused_kernel(
    const double* __restrict__ encW1d, const float* __restrict__ enc_out,
    const float* __restrict__ W2, const float* __restrict__ V,
    const float* __restrict__ x, const int* __restrict__ y,
    const float* __restrict__ W, const double* __restrict__ bR,
    const float* __restrict__ c_init, float* __restrict__ logp_buf,
    float* __restrict__ out_pred)
{
    __shared__ double eW_lds[10][260];   // [u][s], padded
    __shared__ float  W2_lds[10][256];   // [u][k]
    __shared__ float h_lds[2][256];
    __shared__ float di_lds[256];
    __shared__ float e_lds[256];
    __shared__ float rcpZ_s;
    __shared__ float din_s;
    __shared__ double s_V[12];
    __shared__ double s_W2h[12];
    __shared__ double s_ld[256];
    __shared__ double s_red[4];
    __shared__ int s_redi[4];
    __shared__ double s_maxd;
    __shared__ int s_am;

    const int tid  = threadIdx.x;
    const int j    = tid;
    const int wid  = tid >> 6;
    const int lane = tid & 63;
    const int b    = blockIdx.x;

    if (tid < 10) s_V[tid] = (double)V[tid];
    // preload encW1d slice (coalesced global read, transposed LDS write)
    for (int i = tid; i < 2560; i += 256) {
        int s = i / 10, u = i - s * 10;
        eW_lds[u][s] = encW1d[(long)b * 2560 + i];
        W2_lds[i >> 8][i & 255] = W2[i];
    }
    h_lds[0][j] = enc_out[(long)b * 65536 + j * 256 + 255];   // h-major: [j][255]
    float c_f = c_init[(long)b * 256 + j];
    const double bi = bR[j * 4 + 0], bf = bR[j * 4 + 1];
    const double bg = bR[j * 4 + 2], bo = bR[j * 4 + 3];
    const float* wcol = W + j * 4;
    __syncthreads();

    for (int t = 0; t < 256; ++t) {
        const int cur = t & 1, nxt = cur ^ 1;
        const float* hh = h_lds[cur];

        // ---------------- phase A: attention softmax ----------------------
        for (int u = wid; u < 10; u += 4) {
            double p = 0.0;
            #pragma unroll
            for (int i = 0; i < 4; ++i) {
                int k = lane + i * 64;
                p += (double)W2_lds[u][k] * (double)hh[k];
            }
            #pragma unroll
            for (int off = 32; off >= 1; off >>= 1) p += __shfl_down(p, off, 64);
            if (lane == 0) s_W2h[u] = p;
        }
        __syncthreads();

        double l = 0.0;
        #pragma unroll
        for (int u = 0; u < 10; ++u) l += s_V[u] * dtanh_(eW_lds[u][j] + s_W2h[u]);
        s_ld[j] = l;

        {   // argmax (first-index tie-break)
            double v = l; int idx = j;
            #pragma unroll
            for (int off = 32; off >= 1; off >>= 1) {
                double v2 = __shfl_down(v, off, 64);
                int i2 = __shfl_down(idx, off, 64);
                if (v2 > v || (v2 == v && i2 < idx)) { v = v2; idx = i2; }
            }
            if (lane == 0) { s_red[wid] = v; s_redi[wid] = idx; }
        }
        __syncthreads();
        if (tid == 0) {
            double v = s_red[0]; int idx = s_redi[0];
            #pragma unroll
            for (int w2 = 1; w2 < 4; ++w2) {
                if (s_red[w2] > v || (s_red[w2] == v && s_redi[w2] < idx)) {
                    v = s_red[w2]; idx = s_redi[w2];
                }
            }
            s_maxd = v; s_am = idx;
        }
        __syncthreads();

        double e = dexp_(l - s_maxd);
        e_lds[j] = (float)e;
        {
            double v = e;
            #pragma unroll
            for (int off = 32; off >= 1; off >>= 1) v += __shfl_down(v, off, 64);
            if (lane == 0) s_red[wid] = v;
        }
        __syncthreads();
        if (tid == 0) {
            double Z = s_red[0] + s_red[1] + s_red[2] + s_red[3];
            rcpZ_s = (float)(1.0 / Z);
            out_pred[t * 512 + b] = (float)s_am;
            int yv = y[b * 256 + t];
            logp_buf[t * 512 + b] = (float)(s_ld[yv] - s_maxd - log(Z));
        } else if (tid == 1) {   // dec_in (teacher forcing), independent
            float dv = 0.0f;
            if (t > 0) { int yi = y[b * 256 + (t - 1)]; dv = x[b * 256 + yi]; }
            din_s = dv;
        }
        __syncthreads();

        // ------- phase B: di GEMV, contiguous float4 reads (h-major) ------
        {
            const float* ep = enc_out + (long)b * 65536 + j * 256;
            float acc0 = 0.f, acc1 = 0.f, acc2 = 0.f, acc3 = 0.f;
            for (int s2 = 0; s2 < 256; s2 += 4) {
                float4 v = *(const float4*)&ep[s2];
                acc0 += e_lds[s2 + 0] * v.x;
                acc1 += e_lds[s2 + 1] * v.y;
                acc2 += e_lds[s2 + 2] * v.z;
                acc3 += e_lds[s2 + 3] * v.w;
            }
            di_lds[j] = ((acc0 + acc1) + (acc2 + acc3)) * rcpZ_s;
        }
        __syncthreads();   // di_lds ready

        // ---------------- dec LSTM ---------------------------------------
        double A0 = 0, A1 = 0, A2 = 0, A3 = 0;

        // region 1: di (weight rows 0..255)
        fma_range(wcol, 0, di_lds, 0, 256, A0, A1, A2, A3);
        {   // k = 256 : dec_in
            float4 w = *(const float4*)&wcol[256 * 1024];
            float xv = din_s;
            A0 += (double)(w.x * xv); A1 += (double)(w.y * xv);
            A2 += (double)(w.z * xv); A3 += (double)(w.w * xv);
        }
        // region 2: h (weight rows 257..512)
        fma_range(wcol, 257, hh, 0, 256, A0, A1, A2, A3);

        double iv = dsig_(A0 + bi);
        double fv = dsig_(A1 + bf);
        double gv = dtanh_(A2 + bg);
        double ov = dsig_(A3 + bo);
        double c = fv * (double)c_f + iv * gv;
        c_f = (float)c;
        h_lds[nxt][j] = (float)(ov * dtanh_(c));
        __syncthreads();   // publish h_lds[nxt]
    }
}

__global__ __launch_bounds__(256) void loss_kernel(
    const float* __restrict__ logp_buf, float* __restrict__ out)
{
    const int tid = threadIdx.x;
    double acc = 0.0;
    for (int i = tid; i < 131072; i += 256) acc += (double)logp_buf[i];
    __shared__ double s_red[4];
    const int wid = tid >> 6, lane = tid & 63;
    #pragma unroll
    for (int off = 32; off >= 1; off >>= 1) acc += __shfl_down(acc, off, 64);
    if (lane == 0) s_red[wid] = acc;
    __syncthreads();
    if (tid == 0) {
        out[131072] = (float)(-(s_red[0] + s_red[1] + s_red[2] + s_red[3])
                              / (512.0 * 512.0));
    }
}

extern "C" void kernel_launch(void* const* d_in, const int* in_sizes, int n_in,
                              void* d_out, int out_size, void* d_ws, size_t ws_size,
                              hipStream_t stream)
{
    const float* x    = (const float*)d_in[0];
    const int*   y    = (const int*)  d_in[1];
    const float* eWih = (const float*)d_in[2];
    const float* eWhh = (const float*)d_in[3];
    const float* ebih = (const float*)d_in[4];
    const float* ebhh = (const float*)d_in[5];
    const float* dWih = (const float*)d_in[6];
    const float* dWhh = (const float*)d_in[7];
    const float* dbih = (const float*)d_in[8];
    const float* dbhh = (const float*)d_in[9];
    const float* W1   = (const float*)d_in[10];
    const float* W2   = (const float*)d_in[11];
    const float* V    = (const float*)d_in[12];

    double* encW1d = (double*)d_ws;             // 1310720 doubles
    double* bencR  = encW1d + 1310720;          // 1024
    double* bdecR  = bencR + 1024;              // 1024
    float* enc_out = (float*)(bdecR + 1024);    // [512][256][256] (b,s,h) -> (b,h,s)
    float* c_st    = enc_out + 33554432;        // 131072
    float* hzero   = c_st + 131072;             // 131072 (unused)
    float* hd      = hzero + 131072;            // 2 x 131072 (unused)
    float* dibuf   = hd + 262144;               // 131072 (unused)
    float* logp    = dibuf + 131072;            // 131072
    float* WencR   = logp + 131072;             // 263168
    float* WdecR   = WencR + 263168;            // 525312

    float* out = (float*)d_out;

    prep_kernel<<<512, 256, 0, stream>>>(eWih, eWhh, ebih, ebhh,
                                         dWih, dWhh, dbih, dbhh,
                                         WencR, bencR, WdecR, bdecR);

    enc_fused_kernel<<<512, 256, 0, stream>>>(x, WencR, bencR, enc_out, c_st);

    encW1_kernel<<<2048, 256, 0, stream>>>(enc_out, W1, encW1d);

    transpose_kernel<<<512, 256, 0, stream>>>(enc_out);

    dec_fused_kernel<<<512, 256, 0, stream>>>(encW1d, enc_out, W2, V, x, y,
                                              WdecR, bdecR, c_st, logp, out);

    loss_kernel<<<1, 256, 0, stream>>>(logp, out);
}